// Round 1
// baseline (1026.368 us; speedup 1.0000x reference)
//
#include <hip/hip_runtime.h>

#define NN 100000
#define NE 1600000
#define HID 64
#define TXT 384
#define BATCH 1024

// ---------------- CSR build (unordered segment allocation, no scan) ----------
__global__ void k_count(const int* __restrict__ src, const int* __restrict__ dst,
                        int* __restrict__ cntf, int* __restrict__ cntr) {
  int e = blockIdx.x * blockDim.x + threadIdx.x;
  if (e >= NE) return;
  atomicAdd(&cntf[dst[e]], 1);   // forward graph: aggregate into dst
  atomicAdd(&cntr[src[e]], 1);   // reversed graph: aggregate into src
}

__global__ void k_alloc(const int* __restrict__ cntf, const int* __restrict__ cntr,
                        int* __restrict__ startf, int* __restrict__ curf,
                        int* __restrict__ startr, int* __restrict__ curr,
                        int* __restrict__ ctr) {
  int v = blockIdx.x * blockDim.x + threadIdx.x;
  if (v >= NN) return;
  int cf = cntf[v];
  int s = atomicAdd(&ctr[0], cf);
  startf[v] = s; curf[v] = s;
  int cr = cntr[v];
  int t = atomicAdd(&ctr[1], cr);
  startr[v] = t; curr[v] = t;
}

__global__ void k_fill(const int* __restrict__ src, const int* __restrict__ dst,
                       const float* __restrict__ w,
                       int* __restrict__ curf, int* __restrict__ colf, float* __restrict__ valf,
                       int* __restrict__ curr, int* __restrict__ colr, float* __restrict__ valr) {
  int e = blockIdx.x * blockDim.x + threadIdx.x;
  if (e >= NE) return;
  int s = src[e], d = dst[e];
  float we = w[e];
  int p = atomicAdd(&curf[d], 1);
  colf[p] = s; valf[p] = we;
  int q = atomicAdd(&curr[s], 1);
  colr[q] = d; valr[q] = we;
}

// ---------------- weighted-mean aggregation: one wave per row, lane=feature --
__global__ void k_gather(const float* __restrict__ x,
                         const int* __restrict__ start, const int* __restrict__ cnt,
                         const int* __restrict__ col, const float* __restrict__ val,
                         float* __restrict__ out) {
  int wid = (blockIdx.x * blockDim.x + threadIdx.x) >> 6;
  int lane = threadIdx.x & 63;
  if (wid >= NN) return;
  int s = start[wid];
  int c = cnt[wid];
  int e = s + c;
  float acc = 0.f;
  int j = s;
  for (; j + 4 <= e; j += 4) {   // 4-way unroll: 4 independent gathers in flight
    int u0 = col[j], u1 = col[j + 1], u2 = col[j + 2], u3 = col[j + 3];
    float w0 = val[j], w1 = val[j + 1], w2 = val[j + 2], w3 = val[j + 3];
    float x0 = x[u0 * 64 + lane];
    float x1 = x[u1 * 64 + lane];
    float x2 = x[u2 * 64 + lane];
    float x3 = x[u3 * 64 + lane];
    acc += w0 * x0;
    acc += w1 * x1;
    acc += w2 * x2;
    acc += w3 * x3;
  }
  for (; j < e; ++j) acc += val[j] * x[col[j] * 64 + lane];
  float inv = (c > 0) ? 1.0f / (float)c : 0.f;   // DGL mean; zero in-degree -> 0
  out[wid * 64 + lane] = acc * inv;
}

// ---------------- encoder GEMM: [NN,384]@[384,64]+b -> x ---------------------
// M-tile 256, K-chunk 32, 8x8 microtile (256 thr), transposed A-tile in LDS.
__launch_bounds__(256)
__global__ void k_enc(const float* __restrict__ T, const float* __restrict__ W,
                      const float* __restrict__ bias, float* __restrict__ x) {
  __shared__ float As[32][256];
  __shared__ float Bs[32][64];
  const int tid = threadIdx.x;
  const int row0 = blockIdx.x * 256;
  const int rg = tid >> 3, cg = tid & 7;
  float acc[8][8] = {};
  #pragma unroll 1
  for (int ch = 0; ch < 12; ++ch) {
    const int kc = ch * 32;
    const int arow = row0 + tid;
    if (arow < NN) {
      const float* p = T + (size_t)arow * TXT + kc;
      #pragma unroll
      for (int j = 0; j < 32; j += 4) {
        float4 v = *(const float4*)(p + j);
        As[j + 0][tid] = v.x; As[j + 1][tid] = v.y;
        As[j + 2][tid] = v.z; As[j + 3][tid] = v.w;
      }
    } else {
      #pragma unroll
      for (int j = 0; j < 32; ++j) As[j][tid] = 0.f;
    }
    {
      const int i = tid * 8, k = i >> 6, c = i & 63;
      float4 v0 = *(const float4*)(W + (kc + k) * 64 + c);
      float4 v1 = *(const float4*)(W + (kc + k) * 64 + c + 4);
      *(float4*)&Bs[k][c] = v0; *(float4*)&Bs[k][c + 4] = v1;
    }
    __syncthreads();
    #pragma unroll 4
    for (int k = 0; k < 32; ++k) {
      float4 a0 = *(const float4*)&As[k][rg * 8];
      float4 a1 = *(const float4*)&As[k][rg * 8 + 4];
      float4 b0 = *(const float4*)&Bs[k][cg * 8];
      float4 b1 = *(const float4*)&Bs[k][cg * 8 + 4];
      const float a[8] = {a0.x, a0.y, a0.z, a0.w, a1.x, a1.y, a1.z, a1.w};
      const float b[8] = {b0.x, b0.y, b0.z, b0.w, b1.x, b1.y, b1.z, b1.w};
      #pragma unroll
      for (int i = 0; i < 8; ++i)
        #pragma unroll
        for (int jj = 0; jj < 8; ++jj)
          acc[i][jj] = fmaf(a[i], b[jj], acc[i][jj]);
    }
    __syncthreads();
  }
  #pragma unroll
  for (int i = 0; i < 8; ++i) {
    const int row = row0 + rg * 8 + i;
    if (row >= NN) continue;
    #pragma unroll
    for (int j = 0; j < 8; ++j)
      x[(size_t)row * 64 + cg * 8 + j] = acc[i][j] + bias[cg * 8 + j];
  }
}

// ---------------- per-direction combine GEMM: [NN,128]@[128,64] --------------
// A = [x | neigh(pre-scaled)]; B = [Wself ; Wneigh].
// mode 0: yf = acc + bias (pre-relu, stored)
// mode 1: x += relu(yf) + relu(acc + bias)   (skip connection fused)
__launch_bounds__(256)
__global__ void k_gemm(const float* __restrict__ A1, const float* __restrict__ A2,
                       const float* __restrict__ B1, const float* __restrict__ B2,
                       const float* __restrict__ bias,
                       float* __restrict__ yf, float* __restrict__ x, int mode) {
  __shared__ float As[32][256];
  __shared__ float Bs[32][64];
  const int tid = threadIdx.x;
  const int row0 = blockIdx.x * 256;
  const int rg = tid >> 3, cg = tid & 7;
  float acc[8][8] = {};
  #pragma unroll 1
  for (int ch = 0; ch < 4; ++ch) {
    const float* Asrc = (ch < 2) ? A1 : A2;
    const float* Bsrc = (ch < 2) ? B1 : B2;
    const int kc = (ch & 1) * 32;
    const int arow = row0 + tid;
    if (arow < NN) {
      const float* p = Asrc + (size_t)arow * 64 + kc;
      #pragma unroll
      for (int j = 0; j < 32; j += 4) {
        float4 v = *(const float4*)(p + j);
        As[j + 0][tid] = v.x; As[j + 1][tid] = v.y;
        As[j + 2][tid] = v.z; As[j + 3][tid] = v.w;
      }
    } else {
      #pragma unroll
      for (int j = 0; j < 32; ++j) As[j][tid] = 0.f;
    }
    {
      const int i = tid * 8, k = i >> 6, c = i & 63;
      float4 v0 = *(const float4*)(Bsrc + (kc + k) * 64 + c);
      float4 v1 = *(const float4*)(Bsrc + (kc + k) * 64 + c + 4);
      *(float4*)&Bs[k][c] = v0; *(float4*)&Bs[k][c + 4] = v1;
    }
    __syncthreads();
    #pragma unroll 4
    for (int k = 0; k < 32; ++k) {
      float4 a0 = *(const float4*)&As[k][rg * 8];
      float4 a1 = *(const float4*)&As[k][rg * 8 + 4];
      float4 b0 = *(const float4*)&Bs[k][cg * 8];
      float4 b1 = *(const float4*)&Bs[k][cg * 8 + 4];
      const float a[8] = {a0.x, a0.y, a0.z, a0.w, a1.x, a1.y, a1.z, a1.w};
      const float b[8] = {b0.x, b0.y, b0.z, b0.w, b1.x, b1.y, b1.z, b1.w};
      #pragma unroll
      for (int i = 0; i < 8; ++i)
        #pragma unroll
        for (int jj = 0; jj < 8; ++jj)
          acc[i][jj] = fmaf(a[i], b[jj], acc[i][jj]);
    }
    __syncthreads();
  }
  #pragma unroll
  for (int i = 0; i < 8; ++i) {
    const int row = row0 + rg * 8 + i;
    if (row >= NN) continue;
    const int c0 = cg * 8;
    float vv[8];
    #pragma unroll
    for (int j = 0; j < 8; ++j) vv[j] = acc[i][j] + bias[c0 + j];
    if (mode == 0) {
      #pragma unroll
      for (int j = 0; j < 8; ++j) yf[(size_t)row * 64 + c0 + j] = vv[j];
    } else {
      #pragma unroll
      for (int j = 0; j < 8; ++j) {
        size_t idx = (size_t)row * 64 + c0 + j;
        x[idx] += fmaxf(yf[idx], 0.f) + fmaxf(vv[j], 0.f);
      }
    }
  }
}

// ---------------- output gather + L2 normalize -------------------------------
__global__ void k_out(const float* __restrict__ x, const int* __restrict__ ids,
                      float* __restrict__ out) {
  int b = (blockIdx.x * blockDim.x + threadIdx.x) >> 6;
  int lane = threadIdx.x & 63;
  if (b >= BATCH) return;
  int row = ids[b];
  float v = x[(size_t)row * 64 + lane];
  float s = v * v;
  #pragma unroll
  for (int m = 1; m < 64; m <<= 1) s += __shfl_xor(s, m);
  out[b * 64 + lane] = v / sqrtf(s);
}

extern "C" void kernel_launch(void* const* d_in, const int* in_sizes, int n_in,
                              void* d_out, int out_size, void* d_ws, size_t ws_size,
                              hipStream_t stream) {
  const float* text = (const float*)d_in[0];
  const float* wts  = (const float*)d_in[1];
  const float* Wenc = (const float*)d_in[2];
  const float* benc = (const float*)d_in[3];
  const float* Wsf  = (const float*)d_in[4];
  const float* Wnf  = (const float*)d_in[5];
  const float* bf   = (const float*)d_in[6];
  const float* Wsr  = (const float*)d_in[7];
  const float* Wnr  = (const float*)d_in[8];
  const float* br   = (const float*)d_in[9];
  const int*   src  = (const int*)d_in[10];
  const int*   dst  = (const int*)d_in[11];
  const int*   ids  = (const int*)d_in[12];
  float* out = (float*)d_out;

  char* ws = (char*)d_ws;
  size_t o = 0;
  auto alloc = [&](size_t elems) {
    void* p = ws + o;
    o += elems * 4;
    o = (o + 255) & ~(size_t)255;
    return p;
  };
  float* x    = (float*)alloc((size_t)NN * 64);
  float* nf   = (float*)alloc((size_t)NN * 64);
  float* nr   = (float*)alloc((size_t)NN * 64);
  float* yf   = (float*)alloc((size_t)NN * 64);
  float* valf = (float*)alloc(NE);
  float* valr = (float*)alloc(NE);
  int*   colf = (int*)alloc(NE);
  int*   colr = (int*)alloc(NE);
  // ---- zero region start (one memset covers cntf..ctr) ----
  int*   cntf = (int*)alloc(NN);
  int*   cntr = (int*)alloc(NN);
  int*   ctr  = (int*)alloc(64);
  // ---- zero region end ----
  int*   startf = (int*)alloc(NN);
  int*   curf   = (int*)alloc(NN);
  int*   startr = (int*)alloc(NN);
  int*   curr   = (int*)alloc(NN);

  size_t zbytes = (size_t)((char*)startf - (char*)cntf);
  hipMemsetAsync(cntf, 0, zbytes, stream);

  const int EB = (NE + 255) / 256;
  const int VB = (NN + 255) / 256;

  k_count<<<EB, 256, 0, stream>>>(src, dst, cntf, cntr);
  k_alloc<<<VB, 256, 0, stream>>>(cntf, cntr, startf, curf, startr, curr, ctr);
  k_fill<<<EB, 256, 0, stream>>>(src, dst, wts, curf, colf, valf, curr, colr, valr);
  k_enc<<<VB, 256, 0, stream>>>(text, Wenc, benc, x);

  const int GB = ((size_t)NN * 64 + 255) / 256;  // 25000 blocks, 1 wave/row
  for (int l = 0; l < 2; ++l) {
    const float* Wsf_l = Wsf + l * HID * HID;
    const float* Wnf_l = Wnf + l * HID * HID;
    const float* Wsr_l = Wsr + l * HID * HID;
    const float* Wnr_l = Wnr + l * HID * HID;
    const float* bf_l  = bf + l * HID;
    const float* br_l  = br + l * HID;
    k_gather<<<GB, 256, 0, stream>>>(x, startf, cntf, colf, valf, nf);
    k_gather<<<GB, 256, 0, stream>>>(x, startr, cntr, colr, valr, nr);
    k_gemm<<<VB, 256, 0, stream>>>(x, nf, Wsf_l, Wnf_l, bf_l, yf, x, 0);
    k_gemm<<<VB, 256, 0, stream>>>(x, nr, Wsr_l, Wnr_l, br_l, yf, x, 1);
  }
  k_out<<<(BATCH * 64) / 256, 256, 0, stream>>>(x, ids, out);
}